// Round 1
// baseline (2582.263 us; speedup 1.0000x reference)
//
#include <hip/hip_runtime.h>
#include <math.h>

#define NV 54
#define HID 128
#define NDIM 16
#define MLPIN 392   // 3*128 + 8
#define EPSV 1e-5f

// ---------------- conv for hidden layers: Ts[v][k] = b[k] + sum_d Hs[v][d]*W[d][k]
__device__ __forceinline__ void conv_h(const float* __restrict__ W, const float* __restrict__ b,
                                       const float (*Hs)[HID], float (*Ts)[HID], int tid)
{
    const int k  = tid & 127;
    const int vp = tid >> 7;   // row parity this thread owns
    const float bk = b[k];
    #pragma unroll
    for (int c = 0; c < 3; ++c) {
        float acc[9];
        #pragma unroll
        for (int j = 0; j < 9; ++j) acc[j] = bk;
        for (int d = 0; d < HID; d += 4) {
            const float* Wd = W + d * HID + k;
            float w0 = Wd[0], w1 = Wd[HID], w2 = Wd[2*HID], w3 = Wd[3*HID];
            #pragma unroll
            for (int j = 0; j < 9; ++j) {
                int v = vp + 2 * (c * 9 + j);
                float4 hv = *reinterpret_cast<const float4*>(&Hs[v][d]);
                acc[j] = fmaf(hv.x, w0, fmaf(hv.y, w1, fmaf(hv.z, w2, fmaf(hv.w, w3, acc[j]))));
            }
        }
        #pragma unroll
        for (int j = 0; j < 9; ++j) Ts[vp + 2 * (c * 9 + j)][k] = acc[j];
    }
}

// ---------------- adjacency mix + LayerNorm + ReLU (+residual), from Ts into Hs.
// Each wave owns whole rows (v = wid + 4*jj); lane handles cols (lane, lane+64).
// LN reduce = pure wave shfl, no barriers inside the loop.
__device__ __forceinline__ void mix_ln(const float* __restrict__ A,
                                       const float (*Ts)[HID], float (*Hs)[HID],
                                       const float* __restrict__ g, const float* __restrict__ be,
                                       bool residual, int lane, int wid)
{
    const float g0 = g[lane],    g1 = g[lane + 64];
    const float b0 = be[lane],   b1 = be[lane + 64];
    for (int v = wid; v < NV; v += 4) {
        float o0 = 0.f, o1 = 0.f;
        const float* Av = A + v * NV;
        #pragma unroll
        for (int u = 0; u < NV; ++u) {
            float a = Av[u];
            o0 = fmaf(a, Ts[u][lane],      o0);
            o1 = fmaf(a, Ts[u][lane + 64], o1);
        }
        float s  = o0 + o1;
        float sq = o0 * o0 + o1 * o1;
        #pragma unroll
        for (int off = 32; off; off >>= 1) {
            s  += __shfl_xor(s,  off);
            sq += __shfl_xor(sq, off);
        }
        float m   = s * (1.f / 128.f);
        float var = sq * (1.f / 128.f) - m * m;
        float rs  = rsqrtf(var + EPSV);
        float h0 = fmaxf((o0 - m) * rs * g0 + b0, 0.f);
        float h1 = fmaxf((o1 - m) * rs * g1 + b1, 0.f);
        if (residual) { h0 += Hs[v][lane]; h1 += Hs[v][lane + 64]; }
        Hs[v][lane]      = h0;
        Hs[v][lane + 64] = h1;
    }
}

__global__ __launch_bounds__(256, 2) void gcn_fused(
    const float* __restrict__ X, const float* __restrict__ A,
    const int* __restrict__ v1_idx, const int* __restrict__ v2_idx, const int* __restrict__ seat,
    const float* __restrict__ W0, const float* __restrict__ b0,
    const float* __restrict__ g0, const float* __restrict__ be0,
    const float* __restrict__ W1, const float* __restrict__ b1,
    const float* __restrict__ g1, const float* __restrict__ be1,
    const float* __restrict__ W2, const float* __restrict__ b2,
    const float* __restrict__ g2, const float* __restrict__ be2,
    const float* __restrict__ seat_emb,
    const float* __restrict__ mW1, const float* __restrict__ mb1,
    const float* __restrict__ mW2, const float* __restrict__ mb2,
    const float* __restrict__ mW3, const float* __restrict__ mb3,
    const float* __restrict__ rW1, const float* __restrict__ rb1,
    const float* __restrict__ rW2, const float* __restrict__ rb2,
    float* __restrict__ out, int N)
{
    const int n    = blockIdx.x;
    const int tid  = threadIdx.x;
    const int lane = tid & 63;
    const int wid  = tid >> 6;

    __shared__ float Hs[NV][HID];     // 27648 B
    __shared__ float Ts[NV][HID];     // 27648 B
    __shared__ float hbuf[MLPIN];     // 1568 B
    __shared__ float zbuf[HID];       // 512 B
    __shared__ float rbuf[64];        // 256 B

    // ---- conv0: Ts = X @ W0 + b0   (K = 16)
    {
        const int k  = tid & 127;
        const int vp = tid >> 7;
        const float* Xn = X + (size_t)n * NV * NDIM;
        const float bk = b0[k];
        #pragma unroll
        for (int j = 0; j < 27; ++j) {
            int v = vp + 2 * j;
            float acc = bk;
            #pragma unroll
            for (int d = 0; d < NDIM; ++d)
                acc = fmaf(Xn[v * NDIM + d], W0[d * HID + k], acc);
            Ts[v][k] = acc;
        }
    }
    __syncthreads();
    mix_ln(A, Ts, Hs, g0, be0, false, lane, wid);
    __syncthreads();

    conv_h(W1, b1, Hs, Ts, tid);
    __syncthreads();
    mix_ln(A, Ts, Hs, g1, be1, true, lane, wid);
    __syncthreads();

    conv_h(W2, b2, Hs, Ts, tid);
    __syncthreads();
    mix_ln(A, Ts, Hs, g2, be2, true, lane, wid);
    __syncthreads();

    // ---- head: build h = [H[v1], H[v2], mean_v H, seat_emb]  (392)
    {
        const int v1 = v1_idx[n];
        const int v2 = v2_idx[n];
        int st = seat[n];
        st = st < 0 ? 0 : (st > 3 ? 3 : st);
        if (tid < 128) {
            float sum = 0.f;
            #pragma unroll
            for (int v = 0; v < NV; ++v) sum += Hs[v][tid];
            hbuf[tid]       = Hs[v1][tid];
            hbuf[128 + tid] = Hs[v2][tid];
            hbuf[256 + tid] = sum * (1.f / (float)NV);
        } else if (tid < 136) {
            hbuf[384 + (tid - 128)] = seat_emb[st * 8 + (tid - 128)];
        }
    }
    __syncthreads();

    // ---- z1 = relu(h @ mW1 + mb1) on threads 0..127 ; r = relu(h @ rW1 + rb1) on 128..191
    if (tid < 128) {
        float acc = mb1[tid];
        for (int d = 0; d < MLPIN; ++d) acc = fmaf(hbuf[d], mW1[d * 128 + tid], acc);
        zbuf[tid] = fmaxf(acc, 0.f);
    } else if (tid < 192) {
        const int k = tid - 128;
        float acc = rb1[k];
        for (int d = 0; d < MLPIN; ++d) acc = fmaf(hbuf[d], rW1[d * 64 + k], acc);
        rbuf[k] = fmaxf(acc, 0.f);
    }
    __syncthreads();

    if (wid == 0) {
        // z2 = relu(z1 @ mW2 + mb2); win = z2 @ mW3 + mb3
        float acc = mb2[lane];
        #pragma unroll
        for (int d = 0; d < 128; ++d) acc = fmaf(zbuf[d], mW2[d * 64 + lane], acc);
        float z2 = fmaxf(acc, 0.f);
        float p = z2 * mW3[lane];
        #pragma unroll
        for (int off = 32; off; off >>= 1) p += __shfl_xor(p, off);
        if (lane == 0) out[n] = p + mb3[0];
    } else if (wid == 1) {
        // rank = sigmoid(r @ rW2 + rb2)
        float p = rbuf[lane] * rW2[lane];
        #pragma unroll
        for (int off = 32; off; off >>= 1) p += __shfl_xor(p, off);
        if (lane == 0) {
            float rl = p + rb2[0];
            out[N + n] = 1.f / (1.f + expf(-rl));
        }
    }
}

extern "C" void kernel_launch(void* const* d_in, const int* in_sizes, int n_in,
                              void* d_out, int out_size, void* d_ws, size_t ws_size,
                              hipStream_t stream) {
    const float* X        = (const float*)d_in[0];
    const float* A        = (const float*)d_in[1];
    const int*   v1_idx   = (const int*)d_in[2];
    const int*   v2_idx   = (const int*)d_in[3];
    const int*   seat     = (const int*)d_in[4];
    const float* W0       = (const float*)d_in[5];
    const float* b0       = (const float*)d_in[6];
    const float* g0       = (const float*)d_in[7];
    const float* be0      = (const float*)d_in[8];
    const float* W1       = (const float*)d_in[9];
    const float* b1       = (const float*)d_in[10];
    const float* g1       = (const float*)d_in[11];
    const float* be1      = (const float*)d_in[12];
    const float* W2       = (const float*)d_in[13];
    const float* b2       = (const float*)d_in[14];
    const float* g2       = (const float*)d_in[15];
    const float* be2      = (const float*)d_in[16];
    const float* seat_emb = (const float*)d_in[17];
    const float* mW1      = (const float*)d_in[18];
    const float* mb1      = (const float*)d_in[19];
    const float* mW2      = (const float*)d_in[20];
    const float* mb2      = (const float*)d_in[21];
    const float* mW3      = (const float*)d_in[22];
    const float* mb3      = (const float*)d_in[23];
    const float* rW1      = (const float*)d_in[24];
    const float* rb1      = (const float*)d_in[25];
    const float* rW2      = (const float*)d_in[26];
    const float* rb2      = (const float*)d_in[27];

    const int N = in_sizes[2];   // v1_idx length
    float* out = (float*)d_out;

    gcn_fused<<<N, 256, 0, stream>>>(
        X, A, v1_idx, v2_idx, seat,
        W0, b0, g0, be0, W1, b1, g1, be1, W2, b2, g2, be2,
        seat_emb, mW1, mb1, mW2, mb2, mW3, mb3, rW1, rb1, rW2, rb2,
        out, N);
}

// Round 2
// 797.692 us; speedup vs baseline: 3.2372x; 3.2372x over previous
//
#include <hip/hip_runtime.h>
#include <math.h>

// ---------------------------------------------------------------------------
// R2: bf16-MFMA trunk (per-sample GCN fused in LDS) + batched split-bf16 head.
// Kernel A: 2048 blocks x 256 thr, 8 samples/block. Waves split N (cols).
//   LDS: TbF (conv out, B-frag order) 16KB, HbF (H bf16, A-frag order) 16KB,
//        Hf (H fp32 for residual/head) 27KB, Sred (LN partials) 2KB = 62.9KB.
// Kernel B: head GEMMs batched over samples; K=392 dots use hi/lo bf16 split
//   (3 MFMAs) => ~fp32 accuracy. h matrix staged in d_ws as fp32 [N][416].
// ---------------------------------------------------------------------------

typedef __bf16 bf16x8 __attribute__((ext_vector_type(8)));
typedef float  f32x4  __attribute__((ext_vector_type(4)));
typedef unsigned int u32x4 __attribute__((ext_vector_type(4)));

#define DEVINL __device__ __forceinline__

DEVINL unsigned bfr(float x) {             // float -> bf16 bits (RNE)
    unsigned u = __float_as_uint(x);
    return (u + 0x7fffu + ((u >> 16) & 1u)) >> 16;
}
DEVINL unsigned pk2(float a, float b) { return bfr(a) | (bfr(b) << 16); }

DEVINL f32x4 MFMA(u32x4 a, u32x4 b, f32x4 c) {
    return __builtin_amdgcn_mfma_f32_16x16x32_bf16(
        __builtin_bit_cast(bf16x8, a), __builtin_bit_cast(bf16x8, b), c, 0, 0, 0);
}

// ---------------- kernel A helpers -----------------------------------------
// conv acc (D-layout) + bias -> TbF (B-frag order), paired b32 writes.
DEVINL void conv_epi(f32x4 (&acc)[4][2], u32x4* TbF, int w, int g, int c15,
                     float bb0, float bb1)
{
    unsigned* p = (unsigned*)TbF;
    #pragma unroll
    for (int mt = 0; mt < 4; ++mt)
        #pragma unroll
        for (int nt = 0; nt < 2; ++nt) {
            float bb = nt ? bb1 : bb0;
            int lanep = ((mt * 2 + (g >> 1)) & 3) * 16 + c15;
            int unit  = (mt >> 1) * 8 + w * 2 + nt;
            int di = (unit * 64 + lanep) * 4 + (g & 1) * 2;
            p[di]     = pk2(acc[mt][nt][0] + bb, acc[mt][nt][1] + bb);
            p[di + 1] = pk2(acc[mt][nt][2] + bb, acc[mt][nt][3] + bb);
        }
}

DEVINL void do_mix(f32x4 (&acc)[4][2], const u32x4* TbF, const u32x4 (&Af)[4][2],
                   int w, int l)
{
    u32x4 bf[2][2];
    #pragma unroll
    for (int ks = 0; ks < 2; ++ks)
        #pragma unroll
        for (int nt = 0; nt < 2; ++nt)
            bf[ks][nt] = TbF[(ks * 8 + w * 2 + nt) * 64 + l];
    #pragma unroll
    for (int mt = 0; mt < 4; ++mt)
        #pragma unroll
        for (int nt = 0; nt < 2; ++nt) {
            f32x4 a = {0.f, 0.f, 0.f, 0.f};
            a = MFMA(Af[mt][0], bf[0][nt], a);
            a = MFMA(Af[mt][1], bf[1][nt], a);
            acc[mt][nt] = a;
        }
}

// mix acc -> LN(fp32 stats) -> relu -> (+resid from Hf) -> Hf (fp32) + HbF (bf16)
DEVINL void mix_epi(f32x4 (&acc)[4][2], u32x4* HbF, float (*Hf)[128], float (*Sred)[8],
                    int w, int g, int c15,
                    float gc0, float gc1, float bc0, float bc1, bool resid)
{
    #pragma unroll
    for (int mt = 0; mt < 4; ++mt)
        #pragma unroll
        for (int r = 0; r < 4; ++r) {
            float v0 = acc[mt][0][r], v1 = acc[mt][1][r];
            float s = v0 + v1, q = v0 * v0 + v1 * v1;
            #pragma unroll
            for (int m = 1; m <= 8; m <<= 1) { s += __shfl_xor(s, m); q += __shfl_xor(q, m); }
            if (c15 == 0) { int row = mt * 16 + g * 4 + r; Sred[row][w] = s; Sred[row][4 + w] = q; }
        }
    __syncthreads();
    unsigned short* hp = (unsigned short*)HbF;
    #pragma unroll
    for (int mt = 0; mt < 4; ++mt)
        #pragma unroll
        for (int r = 0; r < 4; ++r) {
            int row = mt * 16 + g * 4 + r;
            f32x4 s4 = *(const f32x4*)&Sred[row][0];
            f32x4 q4 = *(const f32x4*)&Sred[row][4];
            float s = s4[0] + s4[1] + s4[2] + s4[3];
            float q = q4[0] + q4[1] + q4[2] + q4[3];
            float m   = s * (1.f / 128.f);
            float var = q * (1.f / 128.f) - m * m;
            float rs  = rsqrtf(var + 1e-5f);
            #pragma unroll
            for (int nt = 0; nt < 2; ++nt) {
                int c = w * 32 + nt * 16 + c15;
                float gc = nt ? gc1 : gc0, bc = nt ? bc1 : bc0;
                float val = fmaxf((acc[mt][nt][r] - m) * rs * gc + bc, 0.f);
                if (row < 54) {
                    if (resid) val += Hf[row][c];
                    Hf[row][c] = val;
                }
                int lanep = ((nt * 2 + (c15 >> 3)) & 3) * 16 + g * 4 + r;
                hp[((w * 4 + mt) * 64 + lanep) * 8 + (c15 & 7)] = (unsigned short)bfr(val);
            }
        }
    __syncthreads();
}

DEVINL void conv12(f32x4 (&acc)[4][2], const u32x4* HbF, const u32x4 (&Wf)[2][4], int l)
{
    #pragma unroll
    for (int mt = 0; mt < 4; ++mt)
        #pragma unroll
        for (int nt = 0; nt < 2; ++nt) acc[mt][nt] = (f32x4){0.f, 0.f, 0.f, 0.f};
    #pragma unroll
    for (int ks = 0; ks < 4; ++ks) {
        u32x4 af[4];
        #pragma unroll
        for (int mt = 0; mt < 4; ++mt) af[mt] = HbF[(ks * 4 + mt) * 64 + l];
        #pragma unroll
        for (int mt = 0; mt < 4; ++mt)
            #pragma unroll
            for (int nt = 0; nt < 2; ++nt)
                acc[mt][nt] = MFMA(af[mt], Wf[nt][ks], acc[mt][nt]);
    }
}

// ---------------- kernel A ---------------------------------------------------
__global__ __launch_bounds__(256, 2) void gcn_mfma(
    const float* __restrict__ X, const float* __restrict__ A,
    const int* __restrict__ v1i, const int* __restrict__ v2i, const int* __restrict__ seat,
    const float* __restrict__ W0, const float* __restrict__ b0v,
    const float* __restrict__ g0v, const float* __restrict__ be0,
    const float* __restrict__ W1, const float* __restrict__ b1v,
    const float* __restrict__ g1v, const float* __restrict__ be1,
    const float* __restrict__ W2, const float* __restrict__ b2v,
    const float* __restrict__ g2v, const float* __restrict__ be2,
    const float* __restrict__ semb, float* __restrict__ hws, int spb)
{
    __shared__ u32x4 TbF[2 * 8 * 64];   // 16KB  unit (ks*8+ntg)
    __shared__ u32x4 HbF[4 * 4 * 64];   // 16KB  unit (ks*4+mt)
    __shared__ float Hf[54][128];       // 27648B fp32 H (residual + head)
    __shared__ float Sred[64][8];       // 2KB   LN partials [row][w]=s,[4+w]=sq

    const int tid = threadIdx.x;
    const int l = tid & 63, w = tid >> 6, g = l >> 4, c15 = l & 15;

    // ---- persistent fragments (built once per block) ----
    u32x4 W0f[2], W1f[2][4], W2f[2][4], Af[4][2];
    float gcs[3][2], bcs[3][2], bbs[3][2];

    #pragma unroll
    for (int nt = 0; nt < 2; ++nt) {
        const int col = w * 32 + nt * 16 + c15;
        #pragma unroll
        for (int ks = 0; ks < 4; ++ks) {
            unsigned t1[4], t2[4];
            #pragma unroll
            for (int jj = 0; jj < 4; ++jj) {
                int k = ks * 32 + g * 8 + 2 * jj;
                t1[jj] = pk2(W1[k * 128 + col], W1[(k + 1) * 128 + col]);
                t2[jj] = pk2(W2[k * 128 + col], W2[(k + 1) * 128 + col]);
            }
            W1f[nt][ks] = (u32x4){t1[0], t1[1], t1[2], t1[3]};
            W2f[nt][ks] = (u32x4){t2[0], t2[1], t2[2], t2[3]};
        }
        {
            unsigned t[4];
            #pragma unroll
            for (int jj = 0; jj < 4; ++jj) {
                int k = g * 8 + 2 * jj;
                t[jj] = (k < 16) ? pk2(W0[k * 128 + col], W0[(k + 1) * 128 + col]) : 0u;
            }
            W0f[nt] = (u32x4){t[0], t[1], t[2], t[3]};
        }
        gcs[0][nt] = g0v[col]; bcs[0][nt] = be0[col]; bbs[0][nt] = b0v[col];
        gcs[1][nt] = g1v[col]; bcs[1][nt] = be1[col]; bbs[1][nt] = b1v[col];
        gcs[2][nt] = g2v[col]; bcs[2][nt] = be2[col]; bbs[2][nt] = b2v[col];
    }
    #pragma unroll
    for (int mt = 0; mt < 4; ++mt) {
        int row = mt * 16 + c15;
        #pragma unroll
        for (int ks = 0; ks < 2; ++ks) {
            unsigned t[4];
            #pragma unroll
            for (int jj = 0; jj < 4; ++jj) {
                int k = ks * 32 + g * 8 + 2 * jj;
                float va = (row < 54 && k     < 54) ? A[row * 54 + k]     : 0.f;
                float vb = (row < 54 && k + 1 < 54) ? A[row * 54 + k + 1] : 0.f;
                t[jj] = pk2(va, vb);
            }
            Af[mt][ks] = (u32x4){t[0], t[1], t[2], t[3]};
        }
    }

    // ---- sample loop ----
    #pragma unroll 1
    for (int it = 0; it < spb; ++it) {
        const int n = blockIdx.x + gridDim.x * it;

        // conv0: A-frags straight from global X (K=16, zero-padded to 32)
        f32x4 acc[4][2];
        #pragma unroll
        for (int mt = 0; mt < 4; ++mt)
            #pragma unroll
            for (int nt = 0; nt < 2; ++nt) acc[mt][nt] = (f32x4){0.f, 0.f, 0.f, 0.f};
        #pragma unroll
        for (int mt = 0; mt < 4; ++mt) {
            int row = mt * 16 + c15;
            u32x4 af;
            if (g < 2 && row < 54) {
                const f32x4* xp = (const f32x4*)(X + (size_t)n * 864 + row * 16 + g * 8);
                f32x4 f0 = xp[0], f1 = xp[1];
                af = (u32x4){pk2(f0[0], f0[1]), pk2(f0[2], f0[3]),
                             pk2(f1[0], f1[1]), pk2(f1[2], f1[3])};
            } else af = (u32x4){0u, 0u, 0u, 0u};
            #pragma unroll
            for (int nt = 0; nt < 2; ++nt) acc[mt][nt] = MFMA(af, W0f[nt], acc[mt][nt]);
        }
        conv_epi(acc, TbF, w, g, c15, bbs[0][0], bbs[0][1]);
        do_mix(acc, TbF, Af, w, l);
        mix_epi(acc, HbF, Hf, Sred, w, g, c15, gcs[0][0], gcs[0][1], bcs[0][0], bcs[0][1], false);

        conv12(acc, HbF, W1f, l);
        conv_epi(acc, TbF, w, g, c15, bbs[1][0], bbs[1][1]);
        do_mix(acc, TbF, Af, w, l);
        mix_epi(acc, HbF, Hf, Sred, w, g, c15, gcs[1][0], gcs[1][1], bcs[1][0], bcs[1][1], true);

        conv12(acc, HbF, W2f, l);
        conv_epi(acc, TbF, w, g, c15, bbs[2][0], bbs[2][1]);
        do_mix(acc, TbF, Af, w, l);
        mix_epi(acc, HbF, Hf, Sred, w, g, c15, gcs[2][0], gcs[2][1], bcs[2][0], bcs[2][1], true);

        // head features -> hws fp32 [N][416] (cols 392..415 zero)
        int v1 = v1i[n], v2 = v2i[n], st = seat[n];
        st = st < 0 ? 0 : (st > 3 ? 3 : st);
        float* hr = hws + (size_t)n * 416;
        if (tid < 128) {
            int c = tid;
            float s = 0.f;
            #pragma unroll
            for (int v = 0; v < 54; ++v) s += Hf[v][c];
            hr[c]       = Hf[v1][c];
            hr[128 + c] = Hf[v2][c];
            hr[256 + c] = s * (1.f / 54.f);
        } else if (tid < 136) {
            hr[384 + (tid - 128)] = semb[st * 8 + (tid - 128)];
        } else if (tid < 160) {
            hr[392 + (tid - 136)] = 0.f;
        }
        // no barrier needed: next write to Hf/HbF happens after next mix's
        // first __syncthreads(); TbF traffic is wave-local.
    }
}

// ---------------- kernel B: batched head -------------------------------------
__global__ __launch_bounds__(256, 2) void head_mfma(
    const float* __restrict__ hws,
    const float* __restrict__ mW1, const float* __restrict__ mb1,
    const float* __restrict__ mW2, const float* __restrict__ mb2,
    const float* __restrict__ mW3, const float* __restrict__ mb3,
    const float* __restrict__ rW1, const float* __restrict__ rb1,
    const float* __restrict__ rW2, const float* __restrict__ rb2,
    float* __restrict__ out, int N)
{
    __shared__ u32x4 pool[2048];          // 32KB
    u32x4* SW1h = pool;                   // [8ntg][64]   (phase 1)
    u32x4* SW1l = pool + 512;
    u32x4* SR1h = pool + 1024;            // [4ntg][64]
    u32x4* Zh   = pool;                   // [4w][4ks2][64] (phase 2, reuse)
    u32x4* SW2h = pool + 1024;            // [4ks2][4ntg][64]

    const int tid = threadIdx.x, l = tid & 63, w = tid >> 6, g = l >> 4, c15 = l & 15;
    const int row = blockIdx.x * 64 + w * 16 + c15;

    f32x4 z1[8], rr[4];
    #pragma unroll
    for (int i = 0; i < 8; ++i) z1[i] = (f32x4){0.f, 0.f, 0.f, 0.f};
    #pragma unroll
    for (int i = 0; i < 4; ++i) rr[i] = (f32x4){0.f, 0.f, 0.f, 0.f};

    for (int ks = 0; ks < 13; ++ks) {
        {   // stage mW1 slice (hi+lo) and rW1 slice (hi) into frag order
            int col = tid & 127, kbase = (tid >> 7) * 16;
            unsigned short* ph = (unsigned short*)SW1h;
            unsigned short* pl = (unsigned short*)SW1l;
            #pragma unroll
            for (int kk = 0; kk < 16; ++kk) {
                int kloc = kbase + kk, k = ks * 32 + kloc;
                float wv = (k < 392) ? mW1[k * 128 + col] : 0.f;
                unsigned hi = bfr(wv);
                float lof = wv - __uint_as_float(hi << 16);
                int idx = ((col >> 4) * 64 + ((kloc >> 3) & 3) * 16 + (col & 15)) * 8 + (kloc & 7);
                ph[idx] = (unsigned short)hi;
                pl[idx] = (unsigned short)bfr(lof);
            }
            int col2 = tid & 63, kb2 = (tid >> 6) * 8;
            unsigned short* pr = (unsigned short*)SR1h;
            #pragma unroll
            for (int kk = 0; kk < 8; ++kk) {
                int kloc = kb2 + kk, k = ks * 32 + kloc;
                float wv = (k < 392) ? rW1[k * 64 + col2] : 0.f;
                pr[((col2 >> 4) * 64 + ((kloc >> 3) & 3) * 16 + (col2 & 15)) * 8 + (kloc & 7)]
                    = (unsigned short)bfr(wv);
            }
        }
        __syncthreads();
        // A-frags from hws (fp32 -> hi/lo bf16)
        const float* hp = hws + (size_t)row * 416 + ks * 32 + g * 8;
        f32x4 f0 = *(const f32x4*)hp, f1 = *(const f32x4*)(hp + 4);
        float vv[8] = {f0[0], f0[1], f0[2], f0[3], f1[0], f1[1], f1[2], f1[3]};
        unsigned th[4], tl[4];
        #pragma unroll
        for (int jj = 0; jj < 4; ++jj) {
            unsigned ha = bfr(vv[2 * jj]), hb = bfr(vv[2 * jj + 1]);
            th[jj] = ha | (hb << 16);
            tl[jj] = pk2(vv[2 * jj] - __uint_as_float(ha << 16),
                         vv[2 * jj + 1] - __uint_as_float(hb << 16));
        }
        u32x4 ah = (u32x4){th[0], th[1], th[2], th[3]};
        u32x4 al = (u32x4){tl[0], tl[1], tl[2], tl[3]};
        #pragma unroll
        for (int nt = 0; nt < 8; ++nt) {
            u32x4 bh = SW1h[nt * 64 + l], bl = SW1l[nt * 64 + l];
            f32x4 a = z1[nt];
            a = MFMA(ah, bh, a); a = MFMA(ah, bl, a); a = MFMA(al, bh, a);
            z1[nt] = a;
        }
        #pragma unroll
        for (int nt = 0; nt < 4; ++nt) rr[nt] = MFMA(ah, SR1h[nt * 64 + l], rr[nt]);
        __syncthreads();
    }

    // rank head: relu(r+rb1) . rW2 -> sigmoid
    float rp[4] = {0.f, 0.f, 0.f, 0.f};
    #pragma unroll
    for (int nt = 0; nt < 4; ++nt) {
        int c = nt * 16 + c15;
        float rb = rb1[c], rw = rW2[c];
        #pragma unroll
        for (int r = 0; r < 4; ++r) rp[r] += fmaxf(rr[nt][r] + rb, 0.f) * rw;
    }
    #pragma unroll
    for (int r = 0; r < 4; ++r) {
        float p = rp[r];
        #pragma unroll
        for (int m = 1; m <= 8; m <<= 1) p += __shfl_xor(p, m);
        if (c15 == 0) {
            int orow = blockIdx.x * 64 + w * 16 + g * 4 + r;
            out[N + orow] = 1.f / (1.f + expf(-(p + rb2[0])));
        }
    }

    // z1 bias+relu -> Z (bf16, A-frag order); stage mW2 frags
    {
        unsigned short* zp = (unsigned short*)Zh;
        #pragma unroll
        for (int nt = 0; nt < 8; ++nt) {
            int c = nt * 16 + c15;
            float bb = mb1[c];
            #pragma unroll
            for (int r = 0; r < 4; ++r) {
                float v = fmaxf(z1[nt][r] + bb, 0.f);
                int lanep = ((nt * 2 + (c15 >> 3)) & 3) * 16 + g * 4 + r;
                zp[((w * 4 + (nt >> 1)) * 64 + lanep) * 8 + (c15 & 7)] = (unsigned short)bfr(v);
            }
        }
        unsigned short* p2 = (unsigned short*)SW2h;
        int col2 = tid & 63, kb = (tid >> 6) * 32;
        #pragma unroll
        for (int kk = 0; kk < 32; ++kk) {
            int k2 = kb + kk;
            p2[(((k2 >> 5) * 4 + (col2 >> 4)) * 64 + ((k2 >> 3) & 3) * 16 + (col2 & 15)) * 8 + (k2 & 7)]
                = (unsigned short)bfr(mW2[k2 * 64 + col2]);
        }
    }
    __syncthreads();

    f32x4 z2a[4];
    #pragma unroll
    for (int i = 0; i < 4; ++i) z2a[i] = (f32x4){0.f, 0.f, 0.f, 0.f};
    #pragma unroll
    for (int ks2 = 0; ks2 < 4; ++ks2) {
        u32x4 za = Zh[(w * 4 + ks2) * 64 + l];
        #pragma unroll
        for (int nt2 = 0; nt2 < 4; ++nt2)
            z2a[nt2] = MFMA(za, SW2h[(ks2 * 4 + nt2) * 64 + l], z2a[nt2]);
    }
    float wp[4] = {0.f, 0.f, 0.f, 0.f};
    #pragma unroll
    for (int nt2 = 0; nt2 < 4; ++nt2) {
        int c = nt2 * 16 + c15;
        float bb = mb2[c], w3 = mW3[c];
        #pragma unroll
        for (int r = 0; r < 4; ++r) wp[r] += fmaxf(z2a[nt2][r] + bb, 0.f) * w3;
    }
    #pragma unroll
    for (int r = 0; r < 4; ++r) {
        float p = wp[r];
        #pragma unroll
        for (int m = 1; m <= 8; m <<= 1) p += __shfl_xor(p, m);
        if (c15 == 0) {
            int orow = blockIdx.x * 64 + w * 16 + g * 4 + r;
            out[orow] = p + mb3[0];
        }
    }
}

extern "C" void kernel_launch(void* const* d_in, const int* in_sizes, int n_in,
                              void* d_out, int out_size, void* d_ws, size_t ws_size,
                              hipStream_t stream) {
    const float* X        = (const float*)d_in[0];
    const float* A        = (const float*)d_in[1];
    const int*   v1_idx   = (const int*)d_in[2];
    const int*   v2_idx   = (const int*)d_in[3];
    const int*   seat     = (const int*)d_in[4];
    const float* W0       = (const float*)d_in[5];
    const float* b0       = (const float*)d_in[6];
    const float* g0       = (const float*)d_in[7];
    const float* be0      = (const float*)d_in[8];
    const float* W1       = (const float*)d_in[9];
    const float* b1       = (const float*)d_in[10];
    const float* g1       = (const float*)d_in[11];
    const float* be1      = (const float*)d_in[12];
    const float* W2       = (const float*)d_in[13];
    const float* b2       = (const float*)d_in[14];
    const float* g2       = (const float*)d_in[15];
    const float* be2      = (const float*)d_in[16];
    const float* seat_emb = (const float*)d_in[17];
    const float* mW1      = (const float*)d_in[18];
    const float* mb1      = (const float*)d_in[19];
    const float* mW2      = (const float*)d_in[20];
    const float* mb2      = (const float*)d_in[21];
    const float* mW3      = (const float*)d_in[22];
    const float* mb3      = (const float*)d_in[23];
    const float* rW1      = (const float*)d_in[24];
    const float* rb1      = (const float*)d_in[25];
    const float* rW2      = (const float*)d_in[26];
    const float* rb2      = (const float*)d_in[27];

    const int N = in_sizes[2];           // 16384
    float* out = (float*)d_out;
    float* hws = (float*)d_ws;           // needs N*416*4 = 27.3MB of ws

    const int spb = 8;
    const int gridA = N / spb;           // 2048
    gcn_mfma<<<gridA, 256, 0, stream>>>(
        X, A, v1_idx, v2_idx, seat,
        W0, b0, g0, be0, W1, b1, g1, be1, W2, b2, g2, be2,
        seat_emb, hws, spb);

    const int gridB = N / 64;            // 256
    head_mfma<<<gridB, 256, 0, stream>>>(
        hws, mW1, mb1, mW2, mb2, mW3, mb3, rW1, rb1, rW2, rb2, out, N);
}